// Round 15
// baseline (181.183 us; speedup 1.0000x reference)
//
#include <hip/hip_runtime.h>
#include <hip/hip_bf16.h>

#define NN 384
#define EE 12288
#define DD 1280
#define HH 128
#define DISROWS (NN*NN)

typedef short bf16x8 __attribute__((ext_vector_type(8)));
typedef short bf16x4 __attribute__((ext_vector_type(4)));
typedef float f32x4  __attribute__((ext_vector_type(4)));

__device__ __forceinline__ unsigned short f2bf(float x){
  unsigned u = __builtin_bit_cast(unsigned, x);
  u += 0x7fffu + ((u >> 16) & 1u);
  return (unsigned short)(u >> 16);
}
__device__ __forceinline__ float bf2f(unsigned short h){
  unsigned u = ((unsigned)h) << 16;
  return __builtin_bit_cast(float, u);
}
__device__ __forceinline__ short f2bf_fast(float x){
  return (short)__bfloat16_as_ushort(__float2bfloat16(x));
}
__device__ __forceinline__ void glds16(const short* g, short* l){
  __builtin_amdgcn_global_load_lds((const __attribute__((address_space(1))) void*)g,
                                   (__attribute__((address_space(3))) void*)l, 16, 0, 0);
}

// transpose W tile -> T[C][R] bf16 hi(+lo). 256-thread variant (small transposes).
__device__ __forceinline__ void tsplit_body(const float* __restrict__ W,
                                            short* __restrict__ Thi, short* __restrict__ Tlo,
                                            int R, int C, int bx, int by, int t,
                                            float* tile){
  int rb = by*64, cb = bx*64;
  int r  = t >> 2;
  int cs = (t & 3) * 16;
  const float* sp = W + (long)(rb + r)*C + cb + cs;
  #pragma unroll
  for (int i = 0; i < 16; i += 4){
    f32x4 v = *(const f32x4*)(sp + i);
    tile[r*65 + cs+i+0] = v[0]; tile[r*65 + cs+i+1] = v[1];
    tile[r*65 + cs+i+2] = v[2]; tile[r*65 + cs+i+3] = v[3];
  }
  __syncthreads();
  int cp = t >> 2;
  int rs = (t & 3) * 16;
  bf16x8 vh0, vh1, vl0, vl1;
  #pragma unroll
  for (int i = 0; i < 8; ++i){
    float f = tile[(rs+i)*65 + cp];
    unsigned short h = f2bf(f);
    vh0[i] = (short)h; vl0[i] = (short)f2bf(f - bf2f(h));
  }
  #pragma unroll
  for (int i = 0; i < 8; ++i){
    float f = tile[(rs+8+i)*65 + cp];
    unsigned short h = f2bf(f);
    vh1[i] = (short)h; vl1[i] = (short)f2bf(f - bf2f(h));
  }
  long ob = (long)(cb + cp)*R + rb + rs;
  *(bf16x8*)&Thi[ob]   = vh0;
  *(bf16x8*)&Thi[ob+8] = vh1;
  if (Tlo){
    *(bf16x8*)&Tlo[ob]   = vl0;
    *(bf16x8*)&Tlo[ob+8] = vl1;
  }
}

// 512-thread variant (R9-verified) for the big 1280x1280 transposes.
__device__ __forceinline__ void tsplit512(const float* __restrict__ W,
                                          short* __restrict__ Thi, short* __restrict__ Tlo,
                                          int R, int C, int bx, int by, int t, float* tile){
  int rb = by*64, cb = bx*64;
  int r = t >> 3, cs = (t & 7)*8;
  const float* sp = W + (long)(rb + r)*C + cb + cs;
  f32x4 v0 = *(const f32x4*)sp;
  f32x4 v1 = *(const f32x4*)(sp + 4);
  tile[r*65 + cs+0] = v0[0]; tile[r*65 + cs+1] = v0[1];
  tile[r*65 + cs+2] = v0[2]; tile[r*65 + cs+3] = v0[3];
  tile[r*65 + cs+4] = v1[0]; tile[r*65 + cs+5] = v1[1];
  tile[r*65 + cs+6] = v1[2]; tile[r*65 + cs+7] = v1[3];
  __syncthreads();
  int cp = t >> 3, rs = (t & 7)*8;
  bf16x8 vh, vl;
  #pragma unroll
  for (int i = 0; i < 8; ++i){
    float f = tile[(rs+i)*65 + cp];
    unsigned short h = f2bf(f);
    vh[i] = (short)h; vl[i] = (short)f2bf(f - bf2f(h));
  }
  long ob = (long)(cb + cp)*R + rb + rs;
  *(bf16x8*)&Thi[ob] = vh;
  if (Tlo) *(bf16x8*)&Tlo[ob] = vl;
}

// ---------------- prep (512 thr): graph CSR | Wd prep | tsplit Wg0 | tsplit Wg1 ----------------
// blocks: [0] graph; [1,42) dw; [42,442) Wg0; [442,842) Wg1
__global__ void k_prep(const int* __restrict__ dst, const float* __restrict__ ef,
                       int* __restrict__ offs, int* __restrict__ sorted,
                       float* __restrict__ ew,
                       const float* __restrict__ Wd1, short* __restrict__ W1t,
                       const float* __restrict__ Wd2, short* __restrict__ W2t,
                       const float* __restrict__ Wg0, short* __restrict__ WtAh,
                       short* __restrict__ WtAl,
                       const float* __restrict__ Wg1, short* __restrict__ WtBh,
                       short* __restrict__ WtBl){
  __shared__ __align__(16) float sh[64*65];
  const int b = blockIdx.x;
  const int t = threadIdx.x;  // 512
  if (b == 0){
    int* cnt = (int*)sh;
    int* base = cnt + 512;
    if (t < 512) cnt[t] = 0;
    __syncthreads();
    for (int e = t; e < EE; e += 512){
      atomicAdd(&cnt[dst[e]], 1);
      float f = ef[e];
      ew[e] = 1.0f/(f*f + 1e-6f);
    }
    __syncthreads();
    for (int off = 1; off < 512; off <<= 1){
      int v = (t >= off) ? cnt[t - off] : 0;
      __syncthreads();
      cnt[t] += v;
      __syncthreads();
    }
    if (t < NN){
      int excl = t ? cnt[t-1] : 0;
      offs[t] = excl;
      base[t] = excl;
    }
    if (t == 0) offs[NN] = EE;
    __syncthreads();
    for (int e = t; e < EE; e += 512){
      int p = atomicAdd(&base[dst[e]], 1);
      sorted[p] = e;
    }
    return;
  }
  if (b < 42){
    int g = b - 1;
    if (g < 40){
      if (t < 256) tsplit_body(Wd1, W1t, nullptr, DD, HH, g & 1, g >> 1, t, sh);
      else { __syncthreads(); }
      return;
    }
    for (int i = t; i < 32*HH; i += 512){
      int c = i >> 7, h = i & 127;
      float v = (c < 30) ? Wd2[h*30 + c] : 0.f;
      W2t[i] = (short)f2bf(v);
    }
    return;
  }
  if (b < 442){
    int g = b - 42;
    tsplit512(Wg0, WtAh, WtAl, DD, DD, g % 20, g / 20, t, sh);
    return;
  }
  {
    int g = b - 442;
    tsplit512(Wg1, WtBh, WtBl, DD, DD, g % 20, g / 20, t, sh);
  }
}

// ---------------- edge aggregation -> split bf16 Yh/Yl ----------------
// X==nullptr: layer0, inline concat (lm/nf). blockIdx.y<4 -> lm cols, ==4 -> nf cols.
__global__ void k_agg(const float* __restrict__ X,
                      const float* __restrict__ lm, const float* __restrict__ nf,
                      const float* __restrict__ ew, const int* __restrict__ src,
                      const int* __restrict__ offs, const int* __restrict__ sorted,
                      short* __restrict__ Yh, short* __restrict__ Yl){
  __shared__ int   s_nd[160];
  __shared__ float s_w[160];
  const int v = blockIdx.x;
  const int y = blockIdx.y;
  const int t = threadIdx.x;
  const int d = y*256 + t;
  float acc;
  if (X)           acc = X[(long)v*DD + d];
  else if (y < 4)  acc = lm[(long)(v+1)*1024 + d];
  else             acc = nf[(long)v*256 + t];
  const int b = offs[v], e = offs[v+1];
  for (int c0 = b; c0 < e; c0 += 160){
    int n = e - c0; if (n > 160) n = 160;
    __syncthreads();
    if (t < n){
      int eid = sorted[c0 + t];
      s_nd[t] = src[eid];
      s_w[t]  = ew[eid];
    }
    __syncthreads();
    if (X){
      int k = 0;
      for (; k + 4 <= n; k += 4){
        acc += s_w[k]  *X[(long)s_nd[k]*DD + d];
        acc += s_w[k+1]*X[(long)s_nd[k+1]*DD + d];
        acc += s_w[k+2]*X[(long)s_nd[k+2]*DD + d];
        acc += s_w[k+3]*X[(long)s_nd[k+3]*DD + d];
      }
      for (; k < n; ++k) acc += s_w[k]*X[(long)s_nd[k]*DD + d];
    } else if (y < 4){
      int k = 0;
      for (; k + 4 <= n; k += 4){
        acc += s_w[k]  *lm[(long)(s_nd[k]+1)*1024 + d];
        acc += s_w[k+1]*lm[(long)(s_nd[k+1]+1)*1024 + d];
        acc += s_w[k+2]*lm[(long)(s_nd[k+2]+1)*1024 + d];
        acc += s_w[k+3]*lm[(long)(s_nd[k+3]+1)*1024 + d];
      }
      for (; k < n; ++k) acc += s_w[k]*lm[(long)(s_nd[k]+1)*1024 + d];
    } else {
      int k = 0;
      for (; k + 4 <= n; k += 4){
        acc += s_w[k]  *nf[(long)s_nd[k]*256 + t];
        acc += s_w[k+1]*nf[(long)s_nd[k+1]*256 + t];
        acc += s_w[k+2]*nf[(long)s_nd[k+2]*256 + t];
        acc += s_w[k+3]*nf[(long)s_nd[k+3]*256 + t];
      }
      for (; k < n; ++k) acc += s_w[k]*nf[(long)s_nd[k]*256 + t];
    }
  }
  unsigned short h = f2bf(acc);
  Yh[(long)v*DD + d] = (short)h;
  Yl[(long)v*DD + d] = (short)f2bf(acc - bf2f(h));
}

// ---------------- GIN GEMM: 64m x 128n, split-K=8, stream-K fixup reduce ----------------
// After writing its P slice, each block atomically bumps cnt[tile]; the 8th finisher
// re-reads the 8 slices (L2-hot), sums in z-order (bit-identical to old k_red),
// adds bias (+ inline lm/nf concat residual when lm != nullptr) and writes Out.
__launch_bounds__(256, 4)
__global__ void k_gin_gemm(const short* __restrict__ Yh, const short* __restrict__ Yl,
                           const short* __restrict__ Whi, const short* __restrict__ Wlo,
                           float* __restrict__ P, int* __restrict__ cnt,
                           const float* __restrict__ bias,
                           const float* __restrict__ lm, const float* __restrict__ nf,
                           float* __restrict__ Out){
  __shared__ __align__(16) short Ahi[64*40], Alo[64*40], Bhi[128*40], Blo[128*40];
  __shared__ int islast;
  const int m0 = blockIdx.x*64;
  const int n0 = blockIdx.y*128;
  const int kbase = blockIdx.z*160;
  const int t = threadIdx.x, w = t >> 6, lane = t & 63;
  const int l15 = lane & 15, l4 = lane >> 4;
  f32x4 acc[8];
  #pragma unroll
  for (int n = 0; n < 8; ++n) acc[n] = (f32x4){0.f,0.f,0.f,0.f};

  const int arow = t >> 2, aq = t & 3;
  const short* aph = Yh  + (long)(m0+arow)*DD + aq*8;
  const short* apl = Yl  + (long)(m0+arow)*DD + aq*8;
  const int brow = t >> 1, bh2 = t & 1;
  const short* bph = Whi + (long)(n0+brow)*DD + bh2*16;
  const short* bpl = Wlo + (long)(n0+brow)*DD + bh2*16;

  for (int kk = 0; kk < 5; ++kk){
    int d0 = kbase + kk*32;
    __syncthreads();
    *(bf16x8*)&Ahi[arow*40 + aq*8] = *(const bf16x8*)(aph + d0);
    *(bf16x8*)&Alo[arow*40 + aq*8] = *(const bf16x8*)(apl + d0);
    *(bf16x8*)&Bhi[brow*40 + bh2*16]     = *(const bf16x8*)(bph + d0);
    *(bf16x8*)&Bhi[brow*40 + bh2*16 + 8] = *(const bf16x8*)(bph + d0 + 8);
    *(bf16x8*)&Blo[brow*40 + bh2*16]     = *(const bf16x8*)(bpl + d0);
    *(bf16x8*)&Blo[brow*40 + bh2*16 + 8] = *(const bf16x8*)(bpl + d0 + 8);
    __syncthreads();

    bf16x8 ah = *(const bf16x8*)&Ahi[(w*16 + l15)*40 + l4*8];
    bf16x8 al = *(const bf16x8*)&Alo[(w*16 + l15)*40 + l4*8];
    #pragma unroll
    for (int n = 0; n < 8; ++n){
      bf16x8 bh = *(const bf16x8*)&Bhi[(n*16 + l15)*40 + l4*8];
      bf16x8 bl = *(const bf16x8*)&Blo[(n*16 + l15)*40 + l4*8];
      acc[n] = __builtin_amdgcn_mfma_f32_16x16x32_bf16(ah, bh, acc[n], 0,0,0);
      acc[n] = __builtin_amdgcn_mfma_f32_16x16x32_bf16(ah, bl, acc[n], 0,0,0);
      acc[n] = __builtin_amdgcn_mfma_f32_16x16x32_bf16(al, bh, acc[n], 0,0,0);
    }
  }
  float* Pz = P + (long)blockIdx.z*NN*DD;
  #pragma unroll
  for (int n = 0; n < 8; ++n){
    int gc = n0 + n*16 + l15;
    #pragma unroll
    for (int r = 0; r < 4; ++r)
      Pz[(long)(m0 + w*16 + l4*4 + r)*DD + gc] = acc[n][r];
  }

  // ---- stream-K fixup ----
  __syncthreads();
  if (t == 0){
    __threadfence();
    int v = atomicAdd(&cnt[blockIdx.x*10 + blockIdx.y], 1);
    islast = (v == 7);
  }
  __syncthreads();
  if (!islast) return;
  __threadfence();
  #pragma unroll
  for (int q = 0; q < 8; ++q){
    int idx = q*256 + t;
    int row = idx >> 5, c4 = idx & 31;       // 128 cols = 32 f32x4
    int grow = m0 + row, gcol = n0 + c4*4;
    long off = (long)grow*DD + gcol;
    f32x4 s = *(const f32x4*)&P[off];
    #pragma unroll
    for (int z = 1; z < 8; ++z)
      s += *(const f32x4*)&P[(long)z*NN*DD + off];
    s += *(const f32x4*)(bias + gcol);
    if (lm){
      f32x4 r = (gcol < 1024) ? *(const f32x4*)(lm + (long)(grow+1)*1024 + gcol)
                              : *(const f32x4*)(nf + (long)grow*256 + gcol - 1024);
      s += r;
    }
    *(f32x4*)&Out[off] = s;
  }
}

// ---------------- fused dis MLP (R11 champion, verbatim) + mask head ----------------
__launch_bounds__(256, 3)
__global__ void k_dis(const float* __restrict__ X, const short* __restrict__ W1t,
                      const float* __restrict__ bd1, const short* __restrict__ W2t,
                      const float* __restrict__ bd2, float* __restrict__ out,
                      const int* __restrict__ midx,
                      const float* __restrict__ Wm1, const float* __restrict__ bm1,
                      const float* __restrict__ Wm2, const float* __restrict__ bm2){
  __shared__ __align__(16) short smem[25088];   // 50176 B
  const int b = blockIdx.x;
  const int t = threadIdx.x;

  if (b >= 600){
    // ---- mask head ----
    float* tl = (float*)smem;
    int m = b - 600;
    if (t < HH){
      const float* x = X + (long)midx[m]*DD;
      float a0 = 0.f, a1 = 0.f, a2 = 0.f, a3 = 0.f;
      for (int d = 0; d < DD; d += 4){
        a0 += x[d]   * Wm1[(d)*HH + t];
        a1 += x[d+1] * Wm1[(d+1)*HH + t];
        a2 += x[d+2] * Wm1[(d+2)*HH + t];
        a3 += x[d+3] * Wm1[(d+3)*HH + t];
      }
      float v = a0 + a1 + a2 + a3 + bm1[t];
      tl[t] = v > 0.f ? v : 0.f;
    }
    __syncthreads();
    if (t < 2){
      float s = bm2[t];
      for (int h = 0; h < HH; ++h) s += tl[h]*Wm2[h*2 + t];
      out[(long)DISROWS*30 + m*2 + t] = tanhf(s);
    }
    return;
  }

  // triangular unrank: ib pairs (2k,2k+1) each have 24-k tiles
  int k = 0, rem = b;
  while (rem >= 2*(24 - k)){ rem -= 2*(24 - k); ++k; }
  int ib = 2*k;
  if (rem >= 24 - k){ ++ib; rem -= 24 - k; }
  const int jb = k + rem;
  const int i0 = ib*8, j0 = jb*16;

  const int w = t >> 6, lane = t & 63;
  const int l15 = lane & 15, l4 = lane >> 4;

  short* WA = smem;                       // [2][128][64] shorts (32768 B)
  float* XF = (float*)(smem + 16384);     // [2][24][68] f32 (13056 B)
  short* TL = smem;                       // alias: [128][136] shorts (34816 B)
  float* OT = (float*)(smem + 17408);     // alias: [128][30] f32 (15360 B)

  f32x4 acc[2][8];
  #pragma unroll
  for (int m = 0; m < 2; ++m)
    #pragma unroll
    for (int n = 0; n < 8; ++n) acc[m][n] = (f32x4){0.f,0.f,0.f,0.f};

  // W staging: wave w, inst i covers h rows [w*32+i*8, +8); lane -> h += lane>>3, slot lane&7
  const short* wsrc[4];
  #pragma unroll
  for (int i = 0; i < 4; ++i){
    int hb = w*32 + i*8 + (lane >> 3);
    wsrc[i] = W1t + (long)hb*DD + (((lane & 7) ^ (hb & 7))*8);
  }
  // X staging: 1536 f32/macro; thread t, g: idx=g*256+t; row=idx>>6 (0..23), col=idx&63
  const float* xsrc[6];
  int xli[6];
  #pragma unroll
  for (int g = 0; g < 6; ++g){
    int idx = g*256 + t;
    int rowl = idx >> 6, col = idx & 63;
    int grow = (rowl < 8) ? (i0 + rowl) : (j0 + rowl - 8);
    xsrc[g] = X + (long)grow*DD + col;
    xli[g] = rowl*68 + col;
  }

  // prologue: macro 0
  float xr[6];
  #pragma unroll
  for (int i = 0; i < 4; ++i)
    glds16(wsrc[i], WA + (w*32 + i*8)*64);
  #pragma unroll
  for (int g = 0; g < 6; ++g) xr[g] = xsrc[g][0];
  #pragma unroll
  for (int g = 0; g < 6; ++g) XF[xli[g]] = xr[g];
  __syncthreads();

  for (int mk = 0; mk < 20; ++mk){
    const int cb = mk & 1;
    short* WAc = WA + cb*8192;
    float* XFc = XF + cb*1632;
    short* WAn = WA + (cb^1)*8192;
    float* XFn = XF + (cb^1)*1632;
    if (mk < 19){
      #pragma unroll
      for (int i = 0; i < 4; ++i)
        glds16(wsrc[i] + (mk+1)*64, WAn + (w*32 + i*8)*64);
      #pragma unroll
      for (int g = 0; g < 6; ++g) xr[g] = xsrc[g][(mk+1)*64];
    }
    #pragma unroll
    for (int ks = 0; ks < 2; ++ks){
      f32x4 xj0 = *(const f32x4*)&XFc[(8 + l15)*68 + ks*32 + l4*8];
      f32x4 xj1 = *(const f32x4*)&XFc[(8 + l15)*68 + ks*32 + l4*8 + 4];
      bf16x8 a[2];
      #pragma unroll
      for (int m = 0; m < 2; ++m){
        const float* xip = &XFc[(2*w + m)*68 + ks*32 + l4*8];
        f32x4 xi0 = *(const f32x4*)xip;
        f32x4 xi1 = *(const f32x4*)(xip + 4);
        f32x4 d0 = xj0 - xi0; d0 = d0*d0;
        f32x4 d1 = xj1 - xi1; d1 = d1*d1;
        bf16x8 av;
        #pragma unroll
        for (int q = 0; q < 4; ++q){
          av[q]   = f2bf_fast(d0[q]);
          av[4+q] = f2bf_fast(d1[q]);
        }
        a[m] = av;
      }
      #pragma unroll
      for (int n = 0; n < 8; ++n){
        bf16x8 wf = *(const bf16x8*)&WAc[(n*16 + l15)*64 + (((ks*4 + l4) ^ (l15 & 7))*8)];
        acc[0][n] = __builtin_amdgcn_mfma_f32_16x16x32_bf16(wf, a[0], acc[0][n], 0,0,0);
        acc[1][n] = __builtin_amdgcn_mfma_f32_16x16x32_bf16(wf, a[1], acc[1][n], 0,0,0);
      }
    }
    if (mk < 19){
      #pragma unroll
      for (int g = 0; g < 6; ++g) XFn[xli[g]] = xr[g];
    }
    __syncthreads();
  }

  // ---- TL[pair][h] write (b64 packed, 4 consecutive h) ----
  f32x4 bd1v[8];
  #pragma unroll
  for (int n = 0; n < 8; ++n) bd1v[n] = *(const f32x4*)(bd1 + n*16 + l4*4);
  #pragma unroll
  for (int m = 0; m < 2; ++m){
    int pair = (2*w + m)*16 + l15;
    #pragma unroll
    for (int n = 0; n < 8; ++n){
      bf16x4 pv;
      #pragma unroll
      for (int r = 0; r < 4; ++r){
        float v = acc[m][n][r] + bd1v[n][r];
        v = v > 0.f ? v : 0.f;
        pv[r] = f2bf_fast(v);
      }
      *(bf16x4*)&TL[pair*136 + n*16 + l4*4] = pv;
    }
  }
  __syncthreads();

  // ---- layer 2: wave w owns pairs [w*32, +32) ----
  f32x4 acc2[2][2];
  #pragma unroll
  for (int m2 = 0; m2 < 2; ++m2)
    #pragma unroll
    for (int nn = 0; nn < 2; ++nn) acc2[m2][nn] = (f32x4){0.f,0.f,0.f,0.f};
  #pragma unroll
  for (int hs = 0; hs < 4; ++hs){
    bf16x8 b2[2];
    #pragma unroll
    for (int nn = 0; nn < 2; ++nn)
      b2[nn] = *(const bf16x8*)&W2t[(nn*16 + l15)*HH + hs*32 + l4*8];
    #pragma unroll
    for (int m2 = 0; m2 < 2; ++m2){
      bf16x8 a2 = *(const bf16x8*)&TL[(w*32 + m2*16 + l15)*136 + hs*32 + l4*8];
      #pragma unroll
      for (int nn = 0; nn < 2; ++nn)
        acc2[m2][nn] = __builtin_amdgcn_mfma_f32_16x16x32_bf16(a2, b2[nn], acc2[m2][nn], 0,0,0);
    }
  }
  // OT[pair][30] f32
  #pragma unroll
  for (int m2 = 0; m2 < 2; ++m2){
    #pragma unroll
    for (int nn = 0; nn < 2; ++nn){
      int cc = nn*16 + l15;
      if (cc < 30){
        float b2v = bd2[cc];
        #pragma unroll
        for (int r = 0; r < 4; ++r)
          OT[(w*32 + m2*16 + l4*4 + r)*30 + cc] = acc2[m2][nn][r] + b2v;
      }
    }
  }
  __syncthreads();

  // ---- coalesced global writes from OT ----
  {
    int i = t >> 5;
    int ca = (t & 31)*15;
    long nbase = ((long)(i0 + i)*NN + j0)*30 + ca;
    const float* nsrc = OT + i*480 + ca;
    #pragma unroll
    for (int q = 0; q < 15; ++q) out[nbase + q] = nsrc[q];
    int j = t >> 4;
    int s = t & 15;
    int ii = s >> 1;
    int c0 = (s & 1)*15;
    long mbase = ((long)(j0 + j)*NN + i0 + ii)*30 + c0;
    const float* msrc = OT + ii*480 + j*30 + c0;
    #pragma unroll
    for (int q = 0; q < 15; ++q) out[mbase + q] = msrc[q];
  }
}

// ---------------- launch ----------------
extern "C" void kernel_launch(void* const* d_in, const int* in_sizes, int n_in,
                              void* d_out, int out_size, void* d_ws, size_t ws_size,
                              hipStream_t stream){
  const float* lm   = (const float*)d_in[0];
  const float* nf   = (const float*)d_in[1];
  const float* ef   = (const float*)d_in[2];
  const int*   src  = (const int*)d_in[3];
  const int*   dst  = (const int*)d_in[4];
  const int*   midx = (const int*)d_in[5];
  const float* Wg0  = (const float*)d_in[6];
  const float* bg0  = (const float*)d_in[7];
  const float* Wg1  = (const float*)d_in[8];
  const float* bg1  = (const float*)d_in[9];
  const float* Wd1  = (const float*)d_in[10];
  const float* bd1  = (const float*)d_in[11];
  const float* Wd2  = (const float*)d_in[12];
  const float* bd2  = (const float*)d_in[13];
  const float* Wm1  = (const float*)d_in[14];
  const float* bm1  = (const float*)d_in[15];
  const float* Wm2  = (const float*)d_in[16];
  const float* bm2  = (const float*)d_in[17];
  float* dis = (float*)d_out;

  char* ws = (char*)d_ws;
  size_t off = 0;
  auto alloc = [&](size_t bytes)->void*{
    void* p = ws + off; off += (bytes + 255) & ~(size_t)255; return p;
  };
  int*   cnt0 = (int*)alloc(256);               // 60 tile counters, layer 0
  int*   cnt1 = (int*)alloc(256);               // 60 tile counters, layer 1
  float* hb0  = (float*)alloc((size_t)NN*DD*4);
  float* hb   = (float*)alloc((size_t)NN*DD*4);
  short* Yh   = (short*)alloc((size_t)NN*DD*2);
  short* Yl   = (short*)alloc((size_t)NN*DD*2);
  float* ew   = (float*)alloc((size_t)EE*4);
  int*   offs = (int*)alloc((NN+1)*4);
  int*   sorted = (int*)alloc(EE*4);
  short* WtAh = (short*)alloc((size_t)DD*DD*2);
  short* WtAl = (short*)alloc((size_t)DD*DD*2);
  short* WtBh = (short*)alloc((size_t)DD*DD*2);
  short* WtBl = (short*)alloc((size_t)DD*DD*2);
  short* W1t  = (short*)alloc((size_t)HH*DD*2);
  short* W2t  = (short*)alloc((size_t)32*HH*2);
  float* P    = (float*)alloc((size_t)8*NN*DD*4);

  hipMemsetAsync(cnt0, 0, 512, stream);   // zeroes cnt0 and cnt1 (adjacent)

  k_prep<<<842,512,0,stream>>>(dst, ef, offs, sorted, ew,
                               Wd1, W1t, Wd2, W2t,
                               Wg0, WtAh, WtAl, Wg1, WtBh, WtBl);

  k_agg<<<dim3(384,5),256,0,stream>>>(nullptr, lm, nf, ew, src, offs, sorted, Yh, Yl);
  k_gin_gemm<<<dim3(6,10,8),256,0,stream>>>(Yh, Yl, WtAh, WtAl, P, cnt0,
                                            bg0, nullptr, nullptr, hb0);

  k_agg<<<dim3(384,5),256,0,stream>>>(hb0, lm, nf, ew, src, offs, sorted, Yh, Yl);
  k_gin_gemm<<<dim3(6,10,8),256,0,stream>>>(Yh, Yl, WtBh, WtBl, P, cnt1,
                                            bg1, lm, nf, hb);

  k_dis<<<664,256,0,stream>>>(hb, W1t, bd1, W2t, bd2, dis,
                              midx, Wm1, bm1, Wm2, bm2);
}

// Round 17
// 120.642 us; speedup vs baseline: 1.5018x; 1.5018x over previous
//
#include <hip/hip_runtime.h>
#include <hip/hip_bf16.h>

#define NN 384
#define EE 12288
#define DD 1280
#define HH 128
#define DISROWS (NN*NN)

typedef short bf16x8 __attribute__((ext_vector_type(8)));
typedef short bf16x4 __attribute__((ext_vector_type(4)));
typedef float f32x4  __attribute__((ext_vector_type(4)));

__device__ __forceinline__ unsigned short f2bf(float x){
  unsigned u = __builtin_bit_cast(unsigned, x);
  u += 0x7fffu + ((u >> 16) & 1u);
  return (unsigned short)(u >> 16);
}
__device__ __forceinline__ float bf2f(unsigned short h){
  unsigned u = ((unsigned)h) << 16;
  return __builtin_bit_cast(float, u);
}
__device__ __forceinline__ short f2bf_fast(float x){
  return (short)__bfloat16_as_ushort(__float2bfloat16(x));
}
__device__ __forceinline__ void glds16(const short* g, short* l){
  __builtin_amdgcn_global_load_lds((const __attribute__((address_space(1))) void*)g,
                                   (__attribute__((address_space(3))) void*)l, 16, 0, 0);
}

// transpose W[R][C] -> Thi/Tlo[C][R] as bf16 hi (+ optional lo residual). 256 threads.
__device__ __forceinline__ void tsplit_body(const float* __restrict__ W,
                                            short* __restrict__ Thi, short* __restrict__ Tlo,
                                            int R, int C, int bx, int by, int t,
                                            float* tile /* [64][65] shared */){
  int rb = by*64, cb = bx*64;
  int r  = t >> 2;
  int cs = (t & 3) * 16;
  const float* sp = W + (long)(rb + r)*C + cb + cs;
  #pragma unroll
  for (int i = 0; i < 16; i += 4){
    f32x4 v = *(const f32x4*)(sp + i);
    tile[r*65 + cs+i+0] = v[0]; tile[r*65 + cs+i+1] = v[1];
    tile[r*65 + cs+i+2] = v[2]; tile[r*65 + cs+i+3] = v[3];
  }
  __syncthreads();
  int cp = t >> 2;
  int rs = (t & 3) * 16;
  bf16x8 vh0, vh1, vl0, vl1;
  #pragma unroll
  for (int i = 0; i < 8; ++i){
    float f = tile[(rs+i)*65 + cp];
    unsigned short h = f2bf(f);
    vh0[i] = (short)h; vl0[i] = (short)f2bf(f - bf2f(h));
  }
  #pragma unroll
  for (int i = 0; i < 8; ++i){
    float f = tile[(rs+8+i)*65 + cp];
    unsigned short h = f2bf(f);
    vh1[i] = (short)h; vl1[i] = (short)f2bf(f - bf2f(h));
  }
  long ob = (long)(cb + cp)*R + rb + rs;
  *(bf16x8*)&Thi[ob]   = vh0;
  *(bf16x8*)&Thi[ob+8] = vh1;
  if (Tlo){
    *(bf16x8*)&Tlo[ob]   = vl0;
    *(bf16x8*)&Tlo[ob+8] = vl1;
  }
}

// ---------------- mega-prep (512 thr): feat | graph CSR | Wd prep | tsplit(Wg0) ----------------
// blocks: [0,960) feat; [960] graph; [961,1002) dw; [1002,1402) tsplit Wg0
__global__ void k_prep(const float* __restrict__ lm, const float* __restrict__ nf,
                       float* __restrict__ x0,
                       const int* __restrict__ dst, const float* __restrict__ ef,
                       int* __restrict__ offs, int* __restrict__ sorted,
                       float* __restrict__ ew,
                       const float* __restrict__ Wd1, short* __restrict__ W1t,
                       const float* __restrict__ Wd2, short* __restrict__ W2t,
                       const float* __restrict__ Wg0, short* __restrict__ WtAh,
                       short* __restrict__ WtAl){
  __shared__ __align__(16) float sh[64*65];
  const int b = blockIdx.x;
  const int t = threadIdx.x;  // 512
  if (b < 960){
    int i = b*512 + t;
    int n = i / 1280;
    int d = i - n*1280;
    x0[i] = (d < 1024) ? lm[(n+1)*1024 + d] : nf[n*256 + (d-1024)];
    return;
  }
  if (b == 960){
    int* cnt = (int*)sh;
    int* base = cnt + 512;
    if (t < 512) cnt[t] = 0;
    __syncthreads();
    for (int e = t; e < EE; e += 512){
      atomicAdd(&cnt[dst[e]], 1);
      float f = ef[e];
      ew[e] = 1.0f/(f*f + 1e-6f);
    }
    __syncthreads();
    for (int off = 1; off < 512; off <<= 1){
      int v = (t >= off) ? cnt[t - off] : 0;
      __syncthreads();
      cnt[t] += v;
      __syncthreads();
    }
    if (t < NN){
      int excl = t ? cnt[t-1] : 0;
      offs[t] = excl;
      base[t] = excl;
    }
    if (t == 0) offs[NN] = EE;
    __syncthreads();
    for (int e = t; e < EE; e += 512){
      int p = atomicAdd(&base[dst[e]], 1);
      sorted[p] = e;
    }
    return;
  }
  if (b < 1002){
    int g = b - 961;
    if (g < 40){
      if (t < 256) tsplit_body(Wd1, W1t, nullptr, DD, HH, g & 1, g >> 1, t, sh);
      else { __syncthreads(); }
      return;
    }
    for (int i = t; i < 32*HH; i += 512){
      int c = i >> 7, h = i & 127;
      float v = (c < 30) ? Wd2[h*30 + c] : 0.f;
      W2t[i] = (short)f2bf(v);
    }
    return;
  }
  {
    int g = b - 1002;
    if (t < 256) tsplit_body(Wg0, WtAh, WtAl, DD, DD, g % 20, g / 20, t, sh);
    else { __syncthreads(); }
  }
}

// ---------------- edge aggregation: writes split bf16 Yh/Yl directly ----------------
__global__ void k_agg(const float* __restrict__ X, const float* __restrict__ ew,
                      const int* __restrict__ src, const int* __restrict__ offs,
                      const int* __restrict__ sorted,
                      short* __restrict__ Yh, short* __restrict__ Yl){
  __shared__ int   s_off[160];
  __shared__ float s_w[160];
  const int v = blockIdx.x;
  const int d = blockIdx.y*256 + threadIdx.x;
  const int t = threadIdx.x;
  float acc = X[(long)v*DD + d];
  const int b = offs[v], e = offs[v+1];
  for (int c0 = b; c0 < e; c0 += 160){
    int n = e - c0; if (n > 160) n = 160;
    __syncthreads();
    if (t < n){
      int eid = sorted[c0 + t];
      s_off[t] = src[eid]*DD;
      s_w[t]   = ew[eid];
    }
    __syncthreads();
    int k = 0;
    for (; k + 4 <= n; k += 4){
      acc += s_w[k]  *X[s_off[k]   + d];
      acc += s_w[k+1]*X[s_off[k+1] + d];
      acc += s_w[k+2]*X[s_off[k+2] + d];
      acc += s_w[k+3]*X[s_off[k+3] + d];
    }
    for (; k < n; ++k) acc += s_w[k]*X[s_off[k] + d];
  }
  unsigned short h = f2bf(acc);
  Yh[(long)v*DD + d] = (short)h;
  Yl[(long)v*DD + d] = (short)f2bf(acc - bf2f(h));
}

// ---------------- GIN GEMM, split-K=8, A pre-split (pure-copy staging) ----------------
__launch_bounds__(256, 2)
__global__ void k_gin_gemm(const short* __restrict__ Yh, const short* __restrict__ Yl,
                           const short* __restrict__ Whi, const short* __restrict__ Wlo,
                           float* __restrict__ P){
  __shared__ __align__(16) short Ahi[128*40], Alo[128*40], Bhi[128*40], Blo[128*40];
  const int m0 = blockIdx.x*128;
  const int n0 = blockIdx.y*128;
  const int kbase = blockIdx.z*160;
  const int t = threadIdx.x, w = t >> 6, lane = t & 63;
  const int l15 = lane & 15, l4 = lane >> 4;
  f32x4 acc[2][8];
  #pragma unroll
  for (int m = 0; m < 2; ++m)
    #pragma unroll
    for (int n = 0; n < 8; ++n) acc[m][n] = (f32x4){0.f,0.f,0.f,0.f};

  const int row = t >> 1, half = t & 1;
  const short* aph = Yh  + (long)(m0+row)*DD + half*16;
  const short* apl = Yl  + (long)(m0+row)*DD + half*16;
  const short* bph = Whi + (long)(n0+row)*DD + half*16;
  const short* bpl = Wlo + (long)(n0+row)*DD + half*16;

  for (int kk = 0; kk < 5; ++kk){
    int d0 = kbase + kk*32;
    __syncthreads();
    *(bf16x8*)&Ahi[row*40 + half*16]     = *(const bf16x8*)(aph + d0);
    *(bf16x8*)&Ahi[row*40 + half*16 + 8] = *(const bf16x8*)(aph + d0 + 8);
    *(bf16x8*)&Alo[row*40 + half*16]     = *(const bf16x8*)(apl + d0);
    *(bf16x8*)&Alo[row*40 + half*16 + 8] = *(const bf16x8*)(apl + d0 + 8);
    *(bf16x8*)&Bhi[row*40 + half*16]     = *(const bf16x8*)(bph + d0);
    *(bf16x8*)&Bhi[row*40 + half*16 + 8] = *(const bf16x8*)(bph + d0 + 8);
    *(bf16x8*)&Blo[row*40 + half*16]     = *(const bf16x8*)(bpl + d0);
    *(bf16x8*)&Blo[row*40 + half*16 + 8] = *(const bf16x8*)(bpl + d0 + 8);
    __syncthreads();

    bf16x8 ah[2], al[2];
    #pragma unroll
    for (int m = 0; m < 2; ++m){
      int rr = w*32 + m*16 + l15;
      ah[m] = *(const bf16x8*)&Ahi[rr*40 + l4*8];
      al[m] = *(const bf16x8*)&Alo[rr*40 + l4*8];
    }
    #pragma unroll
    for (int n = 0; n < 8; ++n){
      int rr = n*16 + l15;
      bf16x8 bh = *(const bf16x8*)&Bhi[rr*40 + l4*8];
      bf16x8 bl = *(const bf16x8*)&Blo[rr*40 + l4*8];
      #pragma unroll
      for (int m = 0; m < 2; ++m){
        acc[m][n] = __builtin_amdgcn_mfma_f32_16x16x32_bf16(ah[m], bh, acc[m][n], 0,0,0);
        acc[m][n] = __builtin_amdgcn_mfma_f32_16x16x32_bf16(ah[m], bl, acc[m][n], 0,0,0);
        acc[m][n] = __builtin_amdgcn_mfma_f32_16x16x32_bf16(al[m], bh, acc[m][n], 0,0,0);
      }
    }
  }
  float* Pz = P + (long)blockIdx.z*NN*DD;
  #pragma unroll
  for (int m = 0; m < 2; ++m){
    #pragma unroll
    for (int n = 0; n < 8; ++n){
      int gr0 = m0 + w*32 + m*16 + l4*4;
      int gc  = n0 + n*16 + l15;
      #pragma unroll
      for (int r = 0; r < 4; ++r)
        Pz[(long)(gr0+r)*DD + gc] = acc[m][n][r];
    }
  }
}

// red: blocks [0,480) sum 8 P slices + bias (+resid) -> Out; blocks [480,880): tsplit(Wg1)
__global__ void k_red_t(const float* __restrict__ P, const float* __restrict__ bias,
                        const float* __restrict__ resid, float* __restrict__ Out,
                        const float* __restrict__ Wg1, short* __restrict__ WtAh,
                        short* __restrict__ WtAl){
  __shared__ __align__(16) float sh[64*65];
  const int b = blockIdx.x;
  if (b >= 480){
    if (Wg1){
      int g = b - 480;
      tsplit_body(Wg1, WtAh, WtAl, DD, DD, g % 20, g / 20, threadIdx.x, sh);
    }
    return;
  }
  const int i = b*256 + threadIdx.x;
  const int col = (i*4) % DD;
  const f32x4* P4 = (const f32x4*)P;
  f32x4 s = P4[i];
  #pragma unroll
  for (int z = 1; z < 8; ++z) s += P4[i + z*122880];
  s += *(const f32x4*)(bias + col);
  if (resid) s += ((const f32x4*)resid)[i];
  ((f32x4*)Out)[i] = s;
}

// ---------------- fused dis MLP (R11 champion + XCD-swizzled blockIdx) + mask head ----------------
// blocks [0,600): tile (ib: 8 i-rows, jb: 16 j-cols), jb_min = ib>>1. 256 thr / 4 waves.
// Block id bijectively remapped (600 % 8 == 0): bb = (b&7)*75 + (b>>3) so each XCD gets a
// contiguous run of 75 triangular tiles (shared i/j rows -> L2 locality). No setprio (R16
// post-timing divergence -> refuted for this structure). blocks [600,664): mask head.
__launch_bounds__(256, 3)
__global__ void k_dis(const float* __restrict__ X, const short* __restrict__ W1t,
                      const float* __restrict__ bd1, const short* __restrict__ W2t,
                      const float* __restrict__ bd2, float* __restrict__ out,
                      const int* __restrict__ midx,
                      const float* __restrict__ Wm1, const float* __restrict__ bm1,
                      const float* __restrict__ Wm2, const float* __restrict__ bm2){
  __shared__ __align__(16) short smem[25088];   // 50176 B
  const int b0 = blockIdx.x;
  const int t = threadIdx.x;

  if (b0 >= 600){
    // ---- mask head ----
    float* tl = (float*)smem;
    int m = b0 - 600;
    if (t < HH){
      const float* x = X + (long)midx[m]*DD;
      float a0 = 0.f, a1 = 0.f, a2 = 0.f, a3 = 0.f;
      for (int d = 0; d < DD; d += 4){
        a0 += x[d]   * Wm1[(d)*HH + t];
        a1 += x[d+1] * Wm1[(d+1)*HH + t];
        a2 += x[d+2] * Wm1[(d+2)*HH + t];
        a3 += x[d+3] * Wm1[(d+3)*HH + t];
      }
      float v = a0 + a1 + a2 + a3 + bm1[t];
      tl[t] = v > 0.f ? v : 0.f;
    }
    __syncthreads();
    if (t < 2){
      float s = bm2[t];
      for (int h = 0; h < HH; ++h) s += tl[h]*Wm2[h*2 + t];
      out[(long)DISROWS*30 + m*2 + t] = tanhf(s);
    }
    return;
  }

  // XCD-aware bijective remap (600 = 8 * 75)
  const int b = (b0 & 7)*75 + (b0 >> 3);

  // triangular unrank: ib pairs (2k,2k+1) each have 24-k tiles
  int k = 0, rem = b;
  while (rem >= 2*(24 - k)){ rem -= 2*(24 - k); ++k; }
  int ib = 2*k;
  if (rem >= 24 - k){ ++ib; rem -= 24 - k; }
  const int jb = k + rem;
  const int i0 = ib*8, j0 = jb*16;

  const int w = t >> 6, lane = t & 63;
  const int l15 = lane & 15, l4 = lane >> 4;

  short* WA = smem;                       // [2][128][64] shorts (32768 B)
  float* XF = (float*)(smem + 16384);     // [2][24][68] f32 (13056 B)
  short* TL = smem;                       // alias: [128][136] shorts (34816 B)
  float* OT = (float*)(smem + 17408);     // alias: [128][30] f32 (15360 B)

  f32x4 acc[2][8];
  #pragma unroll
  for (int m = 0; m < 2; ++m)
    #pragma unroll
    for (int n = 0; n < 8; ++n) acc[m][n] = (f32x4){0.f,0.f,0.f,0.f};

  // W staging: wave w, inst i covers h rows [w*32+i*8, +8); lane -> h += lane>>3, slot lane&7
  const short* wsrc[4];
  #pragma unroll
  for (int i = 0; i < 4; ++i){
    int hb = w*32 + i*8 + (lane >> 3);
    wsrc[i] = W1t + (long)hb*DD + (((lane & 7) ^ (hb & 7))*8);
  }
  // X staging: 1536 f32/macro; thread t, g: idx=g*256+t; row=idx>>6 (0..23), col=idx&63
  const float* xsrc[6];
  int xli[6];
  #pragma unroll
  for (int g = 0; g < 6; ++g){
    int idx = g*256 + t;
    int rowl = idx >> 6, col = idx & 63;
    int grow = (rowl < 8) ? (i0 + rowl) : (j0 + rowl - 8);
    xsrc[g] = X + (long)grow*DD + col;
    xli[g] = rowl*68 + col;
  }

  // prologue: macro 0
  float xr[6];
  #pragma unroll
  for (int i = 0; i < 4; ++i)
    glds16(wsrc[i], WA + (w*32 + i*8)*64);
  #pragma unroll
  for (int g = 0; g < 6; ++g) xr[g] = xsrc[g][0];
  #pragma unroll
  for (int g = 0; g < 6; ++g) XF[xli[g]] = xr[g];
  __syncthreads();

  for (int mk = 0; mk < 20; ++mk){
    const int cb = mk & 1;
    short* WAc = WA + cb*8192;
    float* XFc = XF + cb*1632;
    short* WAn = WA + (cb^1)*8192;
    float* XFn = XF + (cb^1)*1632;
    if (mk < 19){
      #pragma unroll
      for (int i = 0; i < 4; ++i)
        glds16(wsrc[i] + (mk+1)*64, WAn + (w*32 + i*8)*64);
      #pragma unroll
      for (int g = 0; g < 6; ++g) xr[g] = xsrc[g][(mk+1)*64];
    }
    #pragma unroll
    for (int ks = 0; ks < 2; ++ks){
      f32x4 xj0 = *(const f32x4*)&XFc[(8 + l15)*68 + ks*32 + l4*8];
      f32x4 xj1 = *(const f32x4*)&XFc[(8 + l15)*68 + ks*32 + l4*8 + 4];
      bf16x8 a[2];
      #pragma unroll
      for (int m = 0; m < 2; ++m){
        const float* xip = &XFc[(2*w + m)*68 + ks*32 + l4*8];
        f32x4 xi0 = *(const f32x4*)xip;
        f32x4 xi1 = *(const f32x4*)(xip + 4);
        f32x4 d0 = xj0 - xi0; d0 = d0*d0;
        f32x4 d1 = xj1 - xi1; d1 = d1*d1;
        bf16x8 av;
        #pragma unroll
        for (int q = 0; q < 4; ++q){
          av[q]   = f2bf_fast(d0[q]);
          av[4+q] = f2bf_fast(d1[q]);
        }
        a[m] = av;
      }
      #pragma unroll
      for (int n = 0; n < 8; ++n){
        bf16x8 wf = *(const bf16x8*)&WAc[(n*16 + l15)*64 + (((ks*4 + l4) ^ (l15 & 7))*8)];
        acc[0][n] = __builtin_amdgcn_mfma_f32_16x16x32_bf16(wf, a[0], acc[0][n], 0,0,0);
        acc[1][n] = __builtin_amdgcn_mfma_f32_16x16x32_bf16(wf, a[1], acc[1][n], 0,0,0);
      }
    }
    if (mk < 19){
      #pragma unroll
      for (int g = 0; g < 6; ++g) XFn[xli[g]] = xr[g];
    }
    __syncthreads();
  }

  // ---- TL[pair][h] write (b64 packed, 4 consecutive h) ----
  f32x4 bd1v[8];
  #pragma unroll
  for (int n = 0; n < 8; ++n) bd1v[n] = *(const f32x4*)(bd1 + n*16 + l4*4);
  #pragma unroll
  for (int m = 0; m < 2; ++m){
    int pair = (2*w + m)*16 + l15;
    #pragma unroll
    for (int n = 0; n < 8; ++n){
      bf16x4 pv;
      #pragma unroll
      for (int r = 0; r < 4; ++r){
        float v = acc[m][n][r] + bd1v[n][r];
        v = v > 0.f ? v : 0.f;
        pv[r] = f2bf_fast(v);
      }
      *(bf16x4*)&TL[pair*136 + n*16 + l4*4] = pv;
    }
  }
  __syncthreads();

  // ---- layer 2: wave w owns pairs [w*32, +32) ----
  f32x4 acc2[2][2];
  #pragma unroll
  for (int m2 = 0; m2 < 2; ++m2)
    #pragma unroll
    for (int nn = 0; nn < 2; ++nn) acc2[m2][nn] = (f32x4){0.f,0.f,0.f,0.f};
  #pragma unroll
  for (int hs = 0; hs < 4; ++hs){
    bf16x8 b2[2];
    #pragma unroll
    for (int nn = 0; nn < 2; ++nn)
      b2[nn] = *(const bf16x8*)&W2t[(nn*16 + l15)*HH + hs*32 + l4*8];
    #pragma unroll
    for (int m2 = 0; m2 < 2; ++m2){
      bf16x8 a2 = *(const bf16x8*)&TL[(w*32 + m2*16 + l15)*136 + hs*32 + l4*8];
      #pragma unroll
      for (int nn = 0; nn < 2; ++nn)
        acc2[m2][nn] = __builtin_amdgcn_mfma_f32_16x16x32_bf16(a2, b2[nn], acc2[m2][nn], 0,0,0);
    }
  }
  // OT[pair][30] f32
  #pragma unroll
  for (int m2 = 0; m2 < 2; ++m2){
    #pragma unroll
    for (int nn = 0; nn < 2; ++nn){
      int cc = nn*16 + l15;
      if (cc < 30){
        float b2v = bd2[cc];
        #pragma unroll
        for (int r = 0; r < 4; ++r)
          OT[(w*32 + m2*16 + l4*4 + r)*30 + cc] = acc2[m2][nn][r] + b2v;
      }
    }
  }
  __syncthreads();

  // ---- coalesced global writes from OT ----
  {
    int i = t >> 5;
    int ca = (t & 31)*15;
    long nbase = ((long)(i0 + i)*NN + j0)*30 + ca;
    const float* nsrc = OT + i*480 + ca;
    #pragma unroll
    for (int q = 0; q < 15; ++q) out[nbase + q] = nsrc[q];
    int j = t >> 4;
    int s = t & 15;
    int ii = s >> 1;
    int c0 = (s & 1)*15;
    long mbase = ((long)(j0 + j)*NN + i0 + ii)*30 + c0;
    const float* msrc = OT + ii*480 + j*30 + c0;
    #pragma unroll
    for (int q = 0; q < 15; ++q) out[mbase + q] = msrc[q];
  }
}

// ---------------- launch ----------------
extern "C" void kernel_launch(void* const* d_in, const int* in_sizes, int n_in,
                              void* d_out, int out_size, void* d_ws, size_t ws_size,
                              hipStream_t stream){
  const float* lm   = (const float*)d_in[0];
  const float* nf   = (const float*)d_in[1];
  const float* ef   = (const float*)d_in[2];
  const int*   src  = (const int*)d_in[3];
  const int*   dst  = (const int*)d_in[4];
  const int*   midx = (const int*)d_in[5];
  const float* Wg0  = (const float*)d_in[6];
  const float* bg0  = (const float*)d_in[7];
  const float* Wg1  = (const float*)d_in[8];
  const float* bg1  = (const float*)d_in[9];
  const float* Wd1  = (const float*)d_in[10];
  const float* bd1  = (const float*)d_in[11];
  const float* Wd2  = (const float*)d_in[12];
  const float* bd2  = (const float*)d_in[13];
  const float* Wm1  = (const float*)d_in[14];
  const float* bm1  = (const float*)d_in[15];
  const float* Wm2  = (const float*)d_in[16];
  const float* bm2  = (const float*)d_in[17];
  float* dis = (float*)d_out;

  char* ws = (char*)d_ws;
  size_t off = 0;
  auto alloc = [&](size_t bytes)->void*{
    void* p = ws + off; off += (bytes + 255) & ~(size_t)255; return p;
  };
  float* x0   = (float*)alloc((size_t)NN*DD*4);
  float* hb   = (float*)alloc((size_t)NN*DD*4);
  short* Yh   = (short*)alloc((size_t)NN*DD*2);
  short* Yl   = (short*)alloc((size_t)NN*DD*2);
  float* ew   = (float*)alloc((size_t)EE*4);
  int*   offs = (int*)alloc((NN+1)*4);
  int*   sorted = (int*)alloc(EE*4);
  short* WtAh = (short*)alloc((size_t)DD*DD*2);
  short* WtAl = (short*)alloc((size_t)DD*DD*2);
  short* W1t  = (short*)alloc((size_t)HH*DD*2);
  short* W2t  = (short*)alloc((size_t)32*HH*2);
  float* P    = (float*)alloc((size_t)8*NN*DD*4);

  k_prep<<<1402,512,0,stream>>>(lm, nf, x0, dst, ef, offs, sorted, ew,
                                Wd1, W1t, Wd2, W2t, Wg0, WtAh, WtAl);

  k_agg<<<dim3(384,5),256,0,stream>>>(x0, ew, src, offs, sorted, Yh, Yl);
  k_gin_gemm<<<dim3(3,10,8),256,0,stream>>>(Yh, Yl, WtAh, WtAl, P);
  k_red_t<<<880,256,0,stream>>>(P, bg0, nullptr, hb, Wg1, WtAh, WtAl);

  k_agg<<<dim3(384,5),256,0,stream>>>(hb, ew, src, offs, sorted, Yh, Yl);
  k_gin_gemm<<<dim3(3,10,8),256,0,stream>>>(Yh, Yl, WtAh, WtAl, P);
  k_red_t<<<480,256,0,stream>>>(P, bg1, x0, hb, nullptr, nullptr, nullptr);

  k_dis<<<664,256,0,stream>>>(hb, W1t, bd1, W2t, bd2, dis,
                              midx, Wm1, bm1, Wm2, bm2);
}